// Round 12
// baseline (164.490 us; speedup 1.0000x reference)
//
#include <hip/hip_runtime.h>
#include <hip/hip_fp16.h>

// Quaternion message passing v10 (R9 structure + decoupled slot assignment):
//  k_init    : fused  zero cursor[N]  ||  wfrag prep  ||  qT transpose
//  k_slot    : 1 thread/edge: slot=atomicAdd(cursor[dst]); slotbuf[e]=dst*CAP+slot
//              (concentrates atomic latency; coalesced read+write)
//  k_permute : NO atomics/shfls: lanes broadcast-load slotbuf[e]+edge_index[e],
//              stream edge_attr (NT), gather qT row, f16-pack, NT-store the
//              edge's 128B row at its slot
//  k_reduce  : per-node wave: sequential read of <=CAP rows (2 groups in
//              flight), register online softmax (no max-subtract: |z|<~10),
//              residual from qT -> xbuf f16 [N][64]
//  k_mlp     : [N,64]@Wbig1 -> relu -> @Wbig2 via mfma_f32_16x16x32_f16
// Fallback (ws too small or N%16): CSR + int2 scatter + fused gather k_node.

#define FDIM 16
#define CF 64
#define CAP 64   // max degree capacity; Poisson(16) tail ~1e-19 at 64

typedef _Float16 f16x8 __attribute__((ext_vector_type(8)));
typedef float f32x4 __attribute__((ext_vector_type(4)));

// ---- fused init: [0,zb) zero cursor | [zb,zb+32) prep | [zb+32,..) qt ----
__global__ __launch_bounds__(256) void k_init(
    int* __restrict__ cursor, const float* __restrict__ W1,
    const float* __restrict__ W2, _Float16* __restrict__ wfrag,
    const float* __restrict__ q, _Float16* __restrict__ qT,
    int N, int zb) {
  int b = blockIdx.x;
  if (b < zb) {
    int t = b * 256 + threadIdx.x;
    if (t < N) cursor[t] = 0;
  } else if (b < zb + 32) {
    int idx = (b - zb) * 256 + threadIdx.x;
    if (idx >= 8192) return;
    int jj = idx & 7;
    int l  = (idx >> 3) & 63;
    int ks = (idx >> 9) & 1;
    int t  = (idx >> 10) & 3;
    int L  = (idx >> 12) & 1;
    int k = ks * 32 + (l >> 4) * 8 + jj;   // input col (ci*16+fi)
    int j = t * 16 + (l & 15);             // output col (c*16+f)
    int ci = k >> 4, fi = k & 15, c = j >> 4, f = j & 15;
    float sgn = ((0x428Eu >> ((c << 2) | ci)) & 1u) ? -1.f : 1.f;
    const float* W = L ? W2 : W1;
    wfrag[idx] = (_Float16)(sgn * W[(((c ^ ci) * 16) + fi) * 16 + f]);
  } else {
    int t = (b - zb - 32) * 256 + threadIdx.x;   // 8 threads per node
    int n = t >> 3;
    if (n >= N) return;
    int l8 = t & 7;
    int c = l8 >> 1, fh = (l8 & 1) * 8;
    const float4 a = *(const float4*)&q[((size_t)c * N + n) * FDIM + fh];
    const float4 bb = *(const float4*)&q[((size_t)c * N + n) * FDIM + fh + 4];
    f16x8 o;
    o[0]=(_Float16)a.x;  o[1]=(_Float16)a.y;  o[2]=(_Float16)a.z;  o[3]=(_Float16)a.w;
    o[4]=(_Float16)bb.x; o[5]=(_Float16)bb.y; o[6]=(_Float16)bb.z; o[7]=(_Float16)bb.w;
    *(f16x8*)(qT + (size_t)n * CF + l8 * 8) = o;
  }
}

// ---- slot assignment: all atomic latency lives here -----------------------
__global__ __launch_bounds__(256) void k_slot(const int* __restrict__ edge_index,
                                              int* __restrict__ cursor,
                                              int* __restrict__ slotbuf, int E) {
  int e = blockIdx.x * 256 + threadIdx.x;
  if (e >= E) return;
  int dst = edge_index[E + e];
  int slot = atomicAdd(&cursor[dst], 1);
  slotbuf[e] = (slot < CAP) ? dst * CAP + slot : -1;
}

// ---- scatter m2 rows (no atomics, no shfls) -------------------------------
__global__ __launch_bounds__(256) void k_permute(
    const _Float16* __restrict__ qT, const float* __restrict__ edge_attr,
    const int* __restrict__ edge_index, const int* __restrict__ slotbuf,
    _Float16* __restrict__ rows, int N, int E) {
  int t = blockIdx.x * 256 + threadIdx.x;   // 8 threads per edge
  int e = t >> 3;
  if (e >= E) return;
  int l8 = t & 7;
  int c = l8 >> 1, fh = (l8 & 1) * 8;
  int pos = slotbuf[e];                     // 8 lanes same addr -> broadcast
  if (pos < 0) return;                      // overflow guard (P ~ 1e-19)
  int src = edge_index[e];                  // broadcast too
  const float* eap = &edge_attr[((size_t)c * E + e) * FDIM + fh];
  f32x4 ea0 = __builtin_nontemporal_load((const f32x4*)eap);
  f32x4 ea1 = __builtin_nontemporal_load((const f32x4*)(eap + 4));
  const f16x8 qv = *(const f16x8*)(qT + (size_t)src * CF + l8 * 8);
  f16x8 o;
  o[0] = (_Float16)(ea0[0] + (float)qv[0]);
  o[1] = (_Float16)(ea0[1] + (float)qv[1]);
  o[2] = (_Float16)(ea0[2] + (float)qv[2]);
  o[3] = (_Float16)(ea0[3] + (float)qv[3]);
  o[4] = (_Float16)(ea1[0] + (float)qv[4]);
  o[5] = (_Float16)(ea1[1] + (float)qv[5]);
  o[6] = (_Float16)(ea1[2] + (float)qv[6]);
  o[7] = (_Float16)(ea1[3] + (float)qv[7]);
  __builtin_nontemporal_store(
      o, (f16x8*)(rows + (size_t)pos * CF + l8 * 8));
}

// ---- per-node softmax reduce -> xbuf f16 [N][64], 2 groups in flight ------
__global__ __launch_bounds__(256) void k_reduce(
    const _Float16* __restrict__ qT,
    const _Float16* __restrict__ rows,
    const int* __restrict__ cursor,
    const float* __restrict__ beta_p,
    _Float16* __restrict__ xbuf, int N) {
  int tid = threadIdx.x;
  int wave = tid >> 6, l = tid & 63;
  int g = l >> 3, ch = l & 7;           // 8 edge-groups x 8 col-chunks
  int n = blockIdx.x * 4 + wave;
  if (n >= N) return;
  float beta = beta_p[0];
  int cnt = min(cursor[n], CAP);
  size_t base = (size_t)n * CAP;

  float num0=0,num1=0,num2=0,num3=0,num4=0,num5=0,num6=0,num7=0;
  float den0=0,den1=0,den2=0,den3=0,den4=0,den5=0,den6=0,den7=0;
  for (int i = 0; i < cnt; i += 16) {
    int idxA = i + g;
    int idxB = i + 8 + g;
    bool vA = (idxA < cnt);
    bool vB = (idxB < cnt);
    const f16x8 uA = __builtin_nontemporal_load(
        (const f16x8*)(rows + (base + (vA ? idxA : 0)) * CF + ch * 8));
    const f16x8 uB = __builtin_nontemporal_load(
        (const f16x8*)(rows + (base + (vB ? idxB : 0)) * CF + ch * 8));
    float mskA = vA ? 1.f : 0.f;
    float mskB = vB ? 1.f : 0.f;
    {
      float m0=(float)uA[0], m1=(float)uA[1], m2=(float)uA[2], m3=(float)uA[3];
      float m4=(float)uA[4], m5=(float)uA[5], m6=(float)uA[6], m7=(float)uA[7];
      float e0=__expf(m0*beta)*mskA, e1=__expf(m1*beta)*mskA;
      float e2=__expf(m2*beta)*mskA, e3=__expf(m3*beta)*mskA;
      float e4=__expf(m4*beta)*mskA, e5=__expf(m5*beta)*mskA;
      float e6=__expf(m6*beta)*mskA, e7=__expf(m7*beta)*mskA;
      den0+=e0; num0=fmaf(m0,e0,num0); den1+=e1; num1=fmaf(m1,e1,num1);
      den2+=e2; num2=fmaf(m2,e2,num2); den3+=e3; num3=fmaf(m3,e3,num3);
      den4+=e4; num4=fmaf(m4,e4,num4); den5+=e5; num5=fmaf(m5,e5,num5);
      den6+=e6; num6=fmaf(m6,e6,num6); den7+=e7; num7=fmaf(m7,e7,num7);
    }
    {
      float m0=(float)uB[0], m1=(float)uB[1], m2=(float)uB[2], m3=(float)uB[3];
      float m4=(float)uB[4], m5=(float)uB[5], m6=(float)uB[6], m7=(float)uB[7];
      float e0=__expf(m0*beta)*mskB, e1=__expf(m1*beta)*mskB;
      float e2=__expf(m2*beta)*mskB, e3=__expf(m3*beta)*mskB;
      float e4=__expf(m4*beta)*mskB, e5=__expf(m5*beta)*mskB;
      float e6=__expf(m6*beta)*mskB, e7=__expf(m7*beta)*mskB;
      den0+=e0; num0=fmaf(m0,e0,num0); den1+=e1; num1=fmaf(m1,e1,num1);
      den2+=e2; num2=fmaf(m2,e2,num2); den3+=e3; num3=fmaf(m3,e3,num3);
      den4+=e4; num4=fmaf(m4,e4,num4); den5+=e5; num5=fmaf(m5,e5,num5);
      den6+=e6; num6=fmaf(m6,e6,num6); den7+=e7; num7=fmaf(m7,e7,num7);
    }
  }
  #pragma unroll
  for (int off = 8; off <= 32; off <<= 1) {
    num0 += __shfl_xor(num0, off); den0 += __shfl_xor(den0, off);
    num1 += __shfl_xor(num1, off); den1 += __shfl_xor(den1, off);
    num2 += __shfl_xor(num2, off); den2 += __shfl_xor(den2, off);
    num3 += __shfl_xor(num3, off); den3 += __shfl_xor(den3, off);
    num4 += __shfl_xor(num4, off); den4 += __shfl_xor(den4, off);
    num5 += __shfl_xor(num5, off); den5 += __shfl_xor(den5, off);
    num6 += __shfl_xor(num6, off); den6 += __shfl_xor(den6, off);
    num7 += __shfl_xor(num7, off); den7 += __shfl_xor(den7, off);
  }
  if (g == 0) {
    const f16x8 qv = *(const f16x8*)(qT + (size_t)n * CF + ch * 8);
    f16x8 xo;
    xo[0]=(_Float16)((float)qv[0] + (den0>0.f?num0/den0:0.f));
    xo[1]=(_Float16)((float)qv[1] + (den1>0.f?num1/den1:0.f));
    xo[2]=(_Float16)((float)qv[2] + (den2>0.f?num2/den2:0.f));
    xo[3]=(_Float16)((float)qv[3] + (den3>0.f?num3/den3:0.f));
    xo[4]=(_Float16)((float)qv[4] + (den4>0.f?num4/den4:0.f));
    xo[5]=(_Float16)((float)qv[5] + (den5>0.f?num5/den5:0.f));
    xo[6]=(_Float16)((float)qv[6] + (den6>0.f?num6/den6:0.f));
    xo[7]=(_Float16)((float)qv[7] + (den7>0.f?num7/den7:0.f));
    *(f16x8*)(xbuf + (size_t)n * CF + ch * 8) = xo;
  }
}

// ---- MFMA MLP: [N,64]@Wbig1 -> relu -> @Wbig2 -> out ----------------------
#define HL_STRIDE 72
__global__ __launch_bounds__(256) void k_mlp(
    const _Float16* __restrict__ xbuf,
    const _Float16* __restrict__ wfrag,
    const float* __restrict__ b1, const float* __restrict__ b2,
    float* __restrict__ out, int N) {
  __shared__ _Float16 hl[4][16][HL_STRIDE];
  int tid = threadIdx.x, wave = tid >> 6, l = tid & 63;
  int n0 = (blockIdx.x * 4 + wave) * 16;
  bool valid = (n0 < N);
  int nb = valid ? n0 : 0;
  int cl = l & 15, kg = l >> 4;

  const f16x8* wf = (const f16x8*)wfrag;  // [L][t][ks][64]
  f16x8 a0 = *(const f16x8*)(xbuf + ((size_t)(nb + cl)) * CF + kg * 8);
  f16x8 a1 = *(const f16x8*)(xbuf + ((size_t)(nb + cl)) * CF + 32 + kg * 8);

  f32x4 c0 = {0,0,0,0}, c1 = {0,0,0,0}, c2 = {0,0,0,0}, c3 = {0,0,0,0};
  c0 = __builtin_amdgcn_mfma_f32_16x16x32_f16(a0, wf[(0*2+0)*64+l], c0, 0,0,0);
  c0 = __builtin_amdgcn_mfma_f32_16x16x32_f16(a1, wf[(0*2+1)*64+l], c0, 0,0,0);
  c1 = __builtin_amdgcn_mfma_f32_16x16x32_f16(a0, wf[(1*2+0)*64+l], c1, 0,0,0);
  c1 = __builtin_amdgcn_mfma_f32_16x16x32_f16(a1, wf[(1*2+1)*64+l], c1, 0,0,0);
  c2 = __builtin_amdgcn_mfma_f32_16x16x32_f16(a0, wf[(2*2+0)*64+l], c2, 0,0,0);
  c2 = __builtin_amdgcn_mfma_f32_16x16x32_f16(a1, wf[(2*2+1)*64+l], c2, 0,0,0);
  c3 = __builtin_amdgcn_mfma_f32_16x16x32_f16(a0, wf[(3*2+0)*64+l], c3, 0,0,0);
  c3 = __builtin_amdgcn_mfma_f32_16x16x32_f16(a1, wf[(3*2+1)*64+l], c3, 0,0,0);

  float bb0 = b1[0*16+cl], bb1 = b1[1*16+cl], bb2 = b1[2*16+cl], bb3 = b1[3*16+cl];
  #pragma unroll
  for (int r = 0; r < 4; ++r) {
    int row = kg * 4 + r;
    hl[wave][row][0*16+cl] = (_Float16)fmaxf(c0[r] + bb0, 0.f);
    hl[wave][row][1*16+cl] = (_Float16)fmaxf(c1[r] + bb1, 0.f);
    hl[wave][row][2*16+cl] = (_Float16)fmaxf(c2[r] + bb2, 0.f);
    hl[wave][row][3*16+cl] = (_Float16)fmaxf(c3[r] + bb3, 0.f);
  }
  __syncthreads();

  f16x8 h0 = *(const f16x8*)&hl[wave][cl][kg * 8];
  f16x8 h1 = *(const f16x8*)&hl[wave][cl][32 + kg * 8];

  f32x4 d0 = {0,0,0,0}, d1 = {0,0,0,0}, d2 = {0,0,0,0}, d3 = {0,0,0,0};
  d0 = __builtin_amdgcn_mfma_f32_16x16x32_f16(h0, wf[(8+0*2+0)*64+l], d0, 0,0,0);
  d0 = __builtin_amdgcn_mfma_f32_16x16x32_f16(h1, wf[(8+0*2+1)*64+l], d0, 0,0,0);
  d1 = __builtin_amdgcn_mfma_f32_16x16x32_f16(h0, wf[(8+1*2+0)*64+l], d1, 0,0,0);
  d1 = __builtin_amdgcn_mfma_f32_16x16x32_f16(h1, wf[(8+1*2+1)*64+l], d1, 0,0,0);
  d2 = __builtin_amdgcn_mfma_f32_16x16x32_f16(h0, wf[(8+2*2+0)*64+l], d2, 0,0,0);
  d2 = __builtin_amdgcn_mfma_f32_16x16x32_f16(h1, wf[(8+2*2+1)*64+l], d2, 0,0,0);
  d3 = __builtin_amdgcn_mfma_f32_16x16x32_f16(h0, wf[(8+3*2+0)*64+l], d3, 0,0,0);
  d3 = __builtin_amdgcn_mfma_f32_16x16x32_f16(h1, wf[(8+3*2+1)*64+l], d3, 0,0,0);

  if (valid) {
    float cb0 = b2[0*16+cl], cb1 = b2[1*16+cl], cb2 = b2[2*16+cl], cb3 = b2[3*16+cl];
    #pragma unroll
    for (int r = 0; r < 4; ++r) {
      int n = n0 + kg * 4 + r;
      out[((size_t)0 * N + n) * FDIM + cl] = d0[r] + cb0;
      out[((size_t)1 * N + n) * FDIM + cl] = d1[r] + cb1;
      out[((size_t)2 * N + n) * FDIM + cl] = d2[r] + cb2;
      out[((size_t)3 * N + n) * FDIM + cl] = d3[r] + cb3;
    }
  }
}

// ---- fallback: CSR + int2 scatter + fused gather node kernel --------------
__global__ __launch_bounds__(256) void k_zero(int* __restrict__ p, int n) {
  int t = blockIdx.x * 256 + threadIdx.x;
  if (t < n) p[t] = 0;
}

__global__ __launch_bounds__(256) void k_hist(const int* __restrict__ edge_index,
                                              int* __restrict__ counts, int E) {
  int e = blockIdx.x * 256 + threadIdx.x;
  if (e >= E) return;
  atomicAdd(&counts[edge_index[E + e]], 1);
}

__global__ __launch_bounds__(1024) void k_scan_fb(int* __restrict__ counts,
                                                  int* __restrict__ node_start,
                                                  int N, int E) {
  __shared__ int part[1024];
  int t = threadIdx.x;
  int seg = (N + 1023) / 1024;
  int base = t * seg;
  int lim = min(base + seg, N);
  int s = 0;
  for (int i = base; i < lim; ++i) s += counts[i];
  part[t] = s;
  __syncthreads();
  for (int off = 1; off < 1024; off <<= 1) {
    int v = (t >= off) ? part[t - off] : 0;
    __syncthreads();
    part[t] += v;
    __syncthreads();
  }
  int run = part[t] - s;
  for (int i = base; i < lim; ++i) {
    int c = counts[i];
    node_start[i] = run;
    counts[i] = run;
    run += c;
  }
  if (t == 1023) node_start[N] = E;
}

__global__ __launch_bounds__(256) void k_scatter2(const int* __restrict__ edge_index,
                                                  int* __restrict__ cursor,
                                                  int2* __restrict__ sorted, int E) {
  int e = blockIdx.x * 256 + threadIdx.x;
  if (e >= E) return;
  int src = edge_index[e];
  int dst = edge_index[E + e];
  int pos = atomicAdd(&cursor[dst], 1);
  sorted[pos] = make_int2(e, src);
}

__global__ __launch_bounds__(256) void k_node(
    const float* __restrict__ q, const float* __restrict__ edge_attr,
    const int2* __restrict__ sorted, const int* __restrict__ node_start,
    const float* __restrict__ beta_p,
    const float* __restrict__ W1, const float* __restrict__ b1,
    const float* __restrict__ W2, const float* __restrict__ b2,
    float* __restrict__ out, int N, int E) {
  __shared__ float w1s[1024], w2s[1024], b1s[64], b2s[64];
  __shared__ float xs[4][64], hs[4][64];
  int tid = threadIdx.x;
  for (int i = tid; i < 1024; i += 256) { w1s[i] = W1[i]; w2s[i] = W2[i]; }
  if (tid < 64) { b1s[tid] = b1[tid]; b2s[tid] = b2[tid]; }
  int wave = tid >> 6, l = tid & 63, c = l >> 4, f = l & 15;
  int n = blockIdx.x * 4 + wave;
  float beta = beta_p[0];
  float x = 0.f;
  if (n < N) {
    int start = node_start[n], end = node_start[n + 1];
    float den = 0.f, num = 0.f;
    for (int i = start; i < end; ++i) {
      int2 es = sorted[i];
      float qa = q[((size_t)c * N + es.y) * FDIM + f];
      float ea = edge_attr[((size_t)c * E + es.x) * FDIM + f];
      float m2 = qa + ea;
      float ez = __expf(m2 * beta);
      den += ez;
      num = fmaf(m2, ez, num);
    }
    float agg = (den > 0.f) ? num / den : 0.f;
    x = q[((size_t)c * N + n) * FDIM + f] + agg;
  }
  xs[wave][l] = x;
  __syncthreads();
  const unsigned negmask = 0x428Eu;
  float acc = b1s[l];
  #pragma unroll
  for (int ci = 0; ci < 4; ++ci) {
    int wc = c ^ ci;
    float s = ((negmask >> ((c << 2) | ci)) & 1u) ? -1.f : 1.f;
    #pragma unroll
    for (int fi = 0; fi < FDIM; ++fi)
      acc = fmaf(s * xs[wave][ci * FDIM + fi], w1s[wc * 256 + fi * FDIM + f], acc);
  }
  hs[wave][l] = fmaxf(acc, 0.f);
  __syncthreads();
  float acc2 = b2s[l];
  #pragma unroll
  for (int ci = 0; ci < 4; ++ci) {
    int wc = c ^ ci;
    float s = ((negmask >> ((c << 2) | ci)) & 1u) ? -1.f : 1.f;
    #pragma unroll
    for (int fi = 0; fi < FDIM; ++fi)
      acc2 = fmaf(s * hs[wave][ci * FDIM + fi], w2s[wc * 256 + fi * FDIM + f], acc2);
  }
  if (n < N) out[((size_t)c * N + n) * FDIM + f] = acc2;
}

extern "C" void kernel_launch(void* const* d_in, const int* in_sizes, int n_in,
                              void* d_out, int out_size, void* d_ws, size_t ws_size,
                              hipStream_t stream) {
  const float* q         = (const float*)d_in[0];
  const float* edge_attr = (const float*)d_in[1];
  const int*   edge_idx  = (const int*)d_in[2];
  const float* W1        = (const float*)d_in[3];
  const float* b1        = (const float*)d_in[4];
  const float* W2        = (const float*)d_in[5];
  const float* b2        = (const float*)d_in[6];
  const float* beta      = (const float*)d_in[7];

  int N = in_sizes[0] / CF;   // 50000
  int E = in_sizes[2] / 2;    // 800000

  // ws: cursor[N] | slotbuf[E] | wfrag | qT f16[N*64] | xbuf f16[N*64] | rows
  int* cursor = (int*)d_ws;
  int* slotbuf = cursor + N;
  size_t off_w = ((size_t)(N + E) * sizeof(int) + 255) & ~(size_t)255;
  _Float16* wfrag = (_Float16*)((char*)d_ws + off_w);
  size_t off_q = off_w + 8192 * sizeof(_Float16);
  _Float16* qT = (_Float16*)((char*)d_ws + off_q);
  size_t off_x = off_q + (size_t)N * CF * sizeof(_Float16);
  _Float16* xbuf = (_Float16*)((char*)d_ws + off_x);
  size_t off_r = (off_x + (size_t)N * CF * sizeof(_Float16) + 255) & ~(size_t)255;
  _Float16* rows = (_Float16*)((char*)d_ws + off_r);
  size_t needed = off_r + (size_t)N * CAP * CF * sizeof(_Float16);

  if (ws_size >= needed && (N % 16) == 0) {
    int zb = (N + 255) / 256;                 // cursor-zero blocks
    int qb = (N * 8 + 255) / 256;             // qt blocks
    k_init<<<zb + 32 + qb, 256, 0, stream>>>(cursor, W1, W2, wfrag, q, qT, N, zb);
    k_slot<<<(E + 255) / 256, 256, 0, stream>>>(edge_idx, cursor, slotbuf, E);
    k_permute<<<(E * 8 + 255) / 256, 256, 0, stream>>>(qT, edge_attr, edge_idx,
                                                       slotbuf, rows, N, E);
    k_reduce<<<(N + 3) / 4, 256, 0, stream>>>(qT, rows, cursor, beta, xbuf, N);
    k_mlp<<<(N / 16 + 3) / 4, 256, 0, stream>>>(xbuf, wfrag, b1, b2,
                                                (float*)d_out, N);
  } else {
    // fallback: CSR + int2 scatter + fused gather kernel
    int* counts     = (int*)d_ws;
    int* node_start = counts + N;
    size_t off8 = ((size_t)(2 * N + 1) * sizeof(int) + 7) & ~(size_t)7;
    int2* sorted2 = (int2*)((char*)d_ws + off8);
    int eblocks = (E + 255) / 256;
    k_zero<<<(N + 255) / 256, 256, 0, stream>>>(counts, N);
    k_hist<<<eblocks, 256, 0, stream>>>(edge_idx, counts, E);
    k_scan_fb<<<1, 1024, 0, stream>>>(counts, node_start, N, E);
    k_scatter2<<<eblocks, 256, 0, stream>>>(edge_idx, counts, sorted2, E);
    k_node<<<(N + 3) / 4, 256, 0, stream>>>(q, edge_attr, sorted2, node_start,
                                            beta, W1, b1, W2, b2,
                                            (float*)d_out, N, E);
  }
}

// Round 13
// 136.190 us; speedup vs baseline: 1.2078x; 1.2078x over previous
//
#include <hip/hip_runtime.h>
#include <hip/hip_fp16.h>

// Quaternion message passing v11 (= R11, the empirically best structure):
//  k_init    : fused  zero cursor[N]  ||  wfrag prep  ||  qT transpose
//  k_permute : stream edge_attr (NT), gather qT row, f16-pack m2, write the
//              edge's 128B row at  dst*CAP + atomicInc(cursor[dst])
//  k_reduce  : per-node wave: sequential read of its <=CAP rows (2 groups of
//              8 rows in flight), register online softmax (no max-subtract:
//              |z|<~10 fits f32), residual from qT -> xbuf f16 [N][64]
//  k_mlp     : [N,64]@Wbig1 -> relu -> @Wbig2 via mfma_f32_16x16x32_f16
// Fallback (ws too small or N%16): CSR + int2 scatter + fused gather k_node.
//
// Experiment matrix (measured): exact-scatter 136us BEST; gather-reads +44;
// bucket+LDS-atomics +550; fused reduce+mlp +17; decoupled slot +28;
// f32 global atomics +200. Random-128B-write BW (~3.5 TB/s) is the floor.

#define FDIM 16
#define CF 64
#define CAP 64   // max degree capacity; Poisson(16) tail ~1e-19 at 64

typedef _Float16 f16x8 __attribute__((ext_vector_type(8)));
typedef float f32x4 __attribute__((ext_vector_type(4)));

// ---- fused init: [0,zb) zero cursor | [zb,zb+32) prep | [zb+32,..) qt ----
__global__ __launch_bounds__(256) void k_init(
    int* __restrict__ cursor, const float* __restrict__ W1,
    const float* __restrict__ W2, _Float16* __restrict__ wfrag,
    const float* __restrict__ q, _Float16* __restrict__ qT,
    int N, int zb) {
  int b = blockIdx.x;
  if (b < zb) {
    int t = b * 256 + threadIdx.x;
    if (t < N) cursor[t] = 0;
  } else if (b < zb + 32) {
    int idx = (b - zb) * 256 + threadIdx.x;
    if (idx >= 8192) return;
    int jj = idx & 7;
    int l  = (idx >> 3) & 63;
    int ks = (idx >> 9) & 1;
    int t  = (idx >> 10) & 3;
    int L  = (idx >> 12) & 1;
    int k = ks * 32 + (l >> 4) * 8 + jj;   // input col (ci*16+fi)
    int j = t * 16 + (l & 15);             // output col (c*16+f)
    int ci = k >> 4, fi = k & 15, c = j >> 4, f = j & 15;
    float sgn = ((0x428Eu >> ((c << 2) | ci)) & 1u) ? -1.f : 1.f;
    const float* W = L ? W2 : W1;
    wfrag[idx] = (_Float16)(sgn * W[(((c ^ ci) * 16) + fi) * 16 + f]);
  } else {
    int t = (b - zb - 32) * 256 + threadIdx.x;   // 8 threads per node
    int n = t >> 3;
    if (n >= N) return;
    int l8 = t & 7;
    int c = l8 >> 1, fh = (l8 & 1) * 8;
    const float4 a = *(const float4*)&q[((size_t)c * N + n) * FDIM + fh];
    const float4 bb = *(const float4*)&q[((size_t)c * N + n) * FDIM + fh + 4];
    f16x8 o;
    o[0]=(_Float16)a.x;  o[1]=(_Float16)a.y;  o[2]=(_Float16)a.z;  o[3]=(_Float16)a.w;
    o[4]=(_Float16)bb.x; o[5]=(_Float16)bb.y; o[6]=(_Float16)bb.z; o[7]=(_Float16)bb.w;
    *(f16x8*)(qT + (size_t)n * CF + l8 * 8) = o;
  }
}

// ---- scatter m2 rows into per-dst fixed-capacity regions ------------------
__global__ __launch_bounds__(256) void k_permute(
    const _Float16* __restrict__ qT, const float* __restrict__ edge_attr,
    const int* __restrict__ edge_index, int* __restrict__ cursor,
    _Float16* __restrict__ rows, int N, int E) {
  int tid = threadIdx.x;
  int l = tid & 63;
  int wid = tid >> 6;
  int eg = l >> 3, l8 = l & 7;          // wave: 8 edges x 8 chunks(8 cols)
  int c = l8 >> 1, fh = (l8 & 1) * 8;
  int e = blockIdx.x * 32 + wid * 8 + eg;
  bool valid = (e < E);
  int ec = valid ? e : 0;
  int src = 0, slot = 0, dst = 0;
  if (l8 == 0 && valid) {
    src = edge_index[ec];
    dst = edge_index[E + ec];
    slot = atomicAdd(&cursor[dst], 1);
  }
  src  = __shfl(src,  l & 56);
  slot = __shfl(slot, l & 56);
  dst  = __shfl(dst,  l & 56);
  if (!valid || slot >= CAP) return;    // overflow guard (P ~ 1e-19)
  const float* eap = &edge_attr[((size_t)c * E + ec) * FDIM + fh];
  f32x4 ea0 = __builtin_nontemporal_load((const f32x4*)eap);
  f32x4 ea1 = __builtin_nontemporal_load((const f32x4*)(eap + 4));
  const f16x8 qv = *(const f16x8*)(qT + (size_t)src * CF + l8 * 8);
  f16x8 o;
  o[0] = (_Float16)(ea0[0] + (float)qv[0]);
  o[1] = (_Float16)(ea0[1] + (float)qv[1]);
  o[2] = (_Float16)(ea0[2] + (float)qv[2]);
  o[3] = (_Float16)(ea0[3] + (float)qv[3]);
  o[4] = (_Float16)(ea1[0] + (float)qv[4]);
  o[5] = (_Float16)(ea1[1] + (float)qv[5]);
  o[6] = (_Float16)(ea1[2] + (float)qv[6]);
  o[7] = (_Float16)(ea1[3] + (float)qv[7]);
  __builtin_nontemporal_store(
      o, (f16x8*)(rows + ((size_t)dst * CAP + slot) * CF + l8 * 8));
}

// ---- per-node softmax reduce -> xbuf f16 [N][64], 2 groups in flight ------
__global__ __launch_bounds__(256) void k_reduce(
    const _Float16* __restrict__ qT,
    const _Float16* __restrict__ rows,
    const int* __restrict__ cursor,
    const float* __restrict__ beta_p,
    _Float16* __restrict__ xbuf, int N) {
  int tid = threadIdx.x;
  int wave = tid >> 6, l = tid & 63;
  int g = l >> 3, ch = l & 7;           // 8 edge-groups x 8 col-chunks
  int n = blockIdx.x * 4 + wave;
  if (n >= N) return;
  float beta = beta_p[0];
  int cnt = min(cursor[n], CAP);
  size_t base = (size_t)n * CAP;

  float num0=0,num1=0,num2=0,num3=0,num4=0,num5=0,num6=0,num7=0;
  float den0=0,den1=0,den2=0,den3=0,den4=0,den5=0,den6=0,den7=0;
  for (int i = 0; i < cnt; i += 16) {
    int idxA = i + g;
    int idxB = i + 8 + g;
    bool vA = (idxA < cnt);
    bool vB = (idxB < cnt);
    const f16x8 uA = __builtin_nontemporal_load(
        (const f16x8*)(rows + (base + (vA ? idxA : 0)) * CF + ch * 8));
    const f16x8 uB = __builtin_nontemporal_load(
        (const f16x8*)(rows + (base + (vB ? idxB : 0)) * CF + ch * 8));
    float mskA = vA ? 1.f : 0.f;
    float mskB = vB ? 1.f : 0.f;
    {
      float m0=(float)uA[0], m1=(float)uA[1], m2=(float)uA[2], m3=(float)uA[3];
      float m4=(float)uA[4], m5=(float)uA[5], m6=(float)uA[6], m7=(float)uA[7];
      float e0=__expf(m0*beta)*mskA, e1=__expf(m1*beta)*mskA;
      float e2=__expf(m2*beta)*mskA, e3=__expf(m3*beta)*mskA;
      float e4=__expf(m4*beta)*mskA, e5=__expf(m5*beta)*mskA;
      float e6=__expf(m6*beta)*mskA, e7=__expf(m7*beta)*mskA;
      den0+=e0; num0=fmaf(m0,e0,num0); den1+=e1; num1=fmaf(m1,e1,num1);
      den2+=e2; num2=fmaf(m2,e2,num2); den3+=e3; num3=fmaf(m3,e3,num3);
      den4+=e4; num4=fmaf(m4,e4,num4); den5+=e5; num5=fmaf(m5,e5,num5);
      den6+=e6; num6=fmaf(m6,e6,num6); den7+=e7; num7=fmaf(m7,e7,num7);
    }
    {
      float m0=(float)uB[0], m1=(float)uB[1], m2=(float)uB[2], m3=(float)uB[3];
      float m4=(float)uB[4], m5=(float)uB[5], m6=(float)uB[6], m7=(float)uB[7];
      float e0=__expf(m0*beta)*mskB, e1=__expf(m1*beta)*mskB;
      float e2=__expf(m2*beta)*mskB, e3=__expf(m3*beta)*mskB;
      float e4=__expf(m4*beta)*mskB, e5=__expf(m5*beta)*mskB;
      float e6=__expf(m6*beta)*mskB, e7=__expf(m7*beta)*mskB;
      den0+=e0; num0=fmaf(m0,e0,num0); den1+=e1; num1=fmaf(m1,e1,num1);
      den2+=e2; num2=fmaf(m2,e2,num2); den3+=e3; num3=fmaf(m3,e3,num3);
      den4+=e4; num4=fmaf(m4,e4,num4); den5+=e5; num5=fmaf(m5,e5,num5);
      den6+=e6; num6=fmaf(m6,e6,num6); den7+=e7; num7=fmaf(m7,e7,num7);
    }
  }
  #pragma unroll
  for (int off = 8; off <= 32; off <<= 1) {
    num0 += __shfl_xor(num0, off); den0 += __shfl_xor(den0, off);
    num1 += __shfl_xor(num1, off); den1 += __shfl_xor(den1, off);
    num2 += __shfl_xor(num2, off); den2 += __shfl_xor(den2, off);
    num3 += __shfl_xor(num3, off); den3 += __shfl_xor(den3, off);
    num4 += __shfl_xor(num4, off); den4 += __shfl_xor(den4, off);
    num5 += __shfl_xor(num5, off); den5 += __shfl_xor(den5, off);
    num6 += __shfl_xor(num6, off); den6 += __shfl_xor(den6, off);
    num7 += __shfl_xor(num7, off); den7 += __shfl_xor(den7, off);
  }
  if (g == 0) {
    const f16x8 qv = *(const f16x8*)(qT + (size_t)n * CF + ch * 8);
    f16x8 xo;
    xo[0]=(_Float16)((float)qv[0] + (den0>0.f?num0/den0:0.f));
    xo[1]=(_Float16)((float)qv[1] + (den1>0.f?num1/den1:0.f));
    xo[2]=(_Float16)((float)qv[2] + (den2>0.f?num2/den2:0.f));
    xo[3]=(_Float16)((float)qv[3] + (den3>0.f?num3/den3:0.f));
    xo[4]=(_Float16)((float)qv[4] + (den4>0.f?num4/den4:0.f));
    xo[5]=(_Float16)((float)qv[5] + (den5>0.f?num5/den5:0.f));
    xo[6]=(_Float16)((float)qv[6] + (den6>0.f?num6/den6:0.f));
    xo[7]=(_Float16)((float)qv[7] + (den7>0.f?num7/den7:0.f));
    *(f16x8*)(xbuf + (size_t)n * CF + ch * 8) = xo;
  }
}

// ---- MFMA MLP: [N,64]@Wbig1 -> relu -> @Wbig2 -> out ----------------------
#define HL_STRIDE 72
__global__ __launch_bounds__(256) void k_mlp(
    const _Float16* __restrict__ xbuf,
    const _Float16* __restrict__ wfrag,
    const float* __restrict__ b1, const float* __restrict__ b2,
    float* __restrict__ out, int N) {
  __shared__ _Float16 hl[4][16][HL_STRIDE];
  int tid = threadIdx.x, wave = tid >> 6, l = tid & 63;
  int n0 = (blockIdx.x * 4 + wave) * 16;
  bool valid = (n0 < N);
  int nb = valid ? n0 : 0;
  int cl = l & 15, kg = l >> 4;

  const f16x8* wf = (const f16x8*)wfrag;  // [L][t][ks][64]
  f16x8 a0 = *(const f16x8*)(xbuf + ((size_t)(nb + cl)) * CF + kg * 8);
  f16x8 a1 = *(const f16x8*)(xbuf + ((size_t)(nb + cl)) * CF + 32 + kg * 8);

  f32x4 c0 = {0,0,0,0}, c1 = {0,0,0,0}, c2 = {0,0,0,0}, c3 = {0,0,0,0};
  c0 = __builtin_amdgcn_mfma_f32_16x16x32_f16(a0, wf[(0*2+0)*64+l], c0, 0,0,0);
  c0 = __builtin_amdgcn_mfma_f32_16x16x32_f16(a1, wf[(0*2+1)*64+l], c0, 0,0,0);
  c1 = __builtin_amdgcn_mfma_f32_16x16x32_f16(a0, wf[(1*2+0)*64+l], c1, 0,0,0);
  c1 = __builtin_amdgcn_mfma_f32_16x16x32_f16(a1, wf[(1*2+1)*64+l], c1, 0,0,0);
  c2 = __builtin_amdgcn_mfma_f32_16x16x32_f16(a0, wf[(2*2+0)*64+l], c2, 0,0,0);
  c2 = __builtin_amdgcn_mfma_f32_16x16x32_f16(a1, wf[(2*2+1)*64+l], c2, 0,0,0);
  c3 = __builtin_amdgcn_mfma_f32_16x16x32_f16(a0, wf[(3*2+0)*64+l], c3, 0,0,0);
  c3 = __builtin_amdgcn_mfma_f32_16x16x32_f16(a1, wf[(3*2+1)*64+l], c3, 0,0,0);

  float bb0 = b1[0*16+cl], bb1 = b1[1*16+cl], bb2 = b1[2*16+cl], bb3 = b1[3*16+cl];
  #pragma unroll
  for (int r = 0; r < 4; ++r) {
    int row = kg * 4 + r;
    hl[wave][row][0*16+cl] = (_Float16)fmaxf(c0[r] + bb0, 0.f);
    hl[wave][row][1*16+cl] = (_Float16)fmaxf(c1[r] + bb1, 0.f);
    hl[wave][row][2*16+cl] = (_Float16)fmaxf(c2[r] + bb2, 0.f);
    hl[wave][row][3*16+cl] = (_Float16)fmaxf(c3[r] + bb3, 0.f);
  }
  __syncthreads();

  f16x8 h0 = *(const f16x8*)&hl[wave][cl][kg * 8];
  f16x8 h1 = *(const f16x8*)&hl[wave][cl][32 + kg * 8];

  f32x4 d0 = {0,0,0,0}, d1 = {0,0,0,0}, d2 = {0,0,0,0}, d3 = {0,0,0,0};
  d0 = __builtin_amdgcn_mfma_f32_16x16x32_f16(h0, wf[(8+0*2+0)*64+l], d0, 0,0,0);
  d0 = __builtin_amdgcn_mfma_f32_16x16x32_f16(h1, wf[(8+0*2+1)*64+l], d0, 0,0,0);
  d1 = __builtin_amdgcn_mfma_f32_16x16x32_f16(h0, wf[(8+1*2+0)*64+l], d1, 0,0,0);
  d1 = __builtin_amdgcn_mfma_f32_16x16x32_f16(h1, wf[(8+1*2+1)*64+l], d1, 0,0,0);
  d2 = __builtin_amdgcn_mfma_f32_16x16x32_f16(h0, wf[(8+2*2+0)*64+l], d2, 0,0,0);
  d2 = __builtin_amdgcn_mfma_f32_16x16x32_f16(h1, wf[(8+2*2+1)*64+l], d2, 0,0,0);
  d3 = __builtin_amdgcn_mfma_f32_16x16x32_f16(h0, wf[(8+3*2+0)*64+l], d3, 0,0,0);
  d3 = __builtin_amdgcn_mfma_f32_16x16x32_f16(h1, wf[(8+3*2+1)*64+l], d3, 0,0,0);

  if (valid) {
    float cb0 = b2[0*16+cl], cb1 = b2[1*16+cl], cb2 = b2[2*16+cl], cb3 = b2[3*16+cl];
    #pragma unroll
    for (int r = 0; r < 4; ++r) {
      int n = n0 + kg * 4 + r;
      out[((size_t)0 * N + n) * FDIM + cl] = d0[r] + cb0;
      out[((size_t)1 * N + n) * FDIM + cl] = d1[r] + cb1;
      out[((size_t)2 * N + n) * FDIM + cl] = d2[r] + cb2;
      out[((size_t)3 * N + n) * FDIM + cl] = d3[r] + cb3;
    }
  }
}

// ---- fallback: CSR + int2 scatter + fused gather node kernel --------------
__global__ __launch_bounds__(256) void k_zero(int* __restrict__ p, int n) {
  int t = blockIdx.x * 256 + threadIdx.x;
  if (t < n) p[t] = 0;
}

__global__ __launch_bounds__(256) void k_hist(const int* __restrict__ edge_index,
                                              int* __restrict__ counts, int E) {
  int e = blockIdx.x * 256 + threadIdx.x;
  if (e >= E) return;
  atomicAdd(&counts[edge_index[E + e]], 1);
}

__global__ __launch_bounds__(1024) void k_scan_fb(int* __restrict__ counts,
                                                  int* __restrict__ node_start,
                                                  int N, int E) {
  __shared__ int part[1024];
  int t = threadIdx.x;
  int seg = (N + 1023) / 1024;
  int base = t * seg;
  int lim = min(base + seg, N);
  int s = 0;
  for (int i = base; i < lim; ++i) s += counts[i];
  part[t] = s;
  __syncthreads();
  for (int off = 1; off < 1024; off <<= 1) {
    int v = (t >= off) ? part[t - off] : 0;
    __syncthreads();
    part[t] += v;
    __syncthreads();
  }
  int run = part[t] - s;
  for (int i = base; i < lim; ++i) {
    int c = counts[i];
    node_start[i] = run;
    counts[i] = run;
    run += c;
  }
  if (t == 1023) node_start[N] = E;
}

__global__ __launch_bounds__(256) void k_scatter2(const int* __restrict__ edge_index,
                                                  int* __restrict__ cursor,
                                                  int2* __restrict__ sorted, int E) {
  int e = blockIdx.x * 256 + threadIdx.x;
  if (e >= E) return;
  int src = edge_index[e];
  int dst = edge_index[E + e];
  int pos = atomicAdd(&cursor[dst], 1);
  sorted[pos] = make_int2(e, src);
}

__global__ __launch_bounds__(256) void k_node(
    const float* __restrict__ q, const float* __restrict__ edge_attr,
    const int2* __restrict__ sorted, const int* __restrict__ node_start,
    const float* __restrict__ beta_p,
    const float* __restrict__ W1, const float* __restrict__ b1,
    const float* __restrict__ W2, const float* __restrict__ b2,
    float* __restrict__ out, int N, int E) {
  __shared__ float w1s[1024], w2s[1024], b1s[64], b2s[64];
  __shared__ float xs[4][64], hs[4][64];
  int tid = threadIdx.x;
  for (int i = tid; i < 1024; i += 256) { w1s[i] = W1[i]; w2s[i] = W2[i]; }
  if (tid < 64) { b1s[tid] = b1[tid]; b2s[tid] = b2[tid]; }
  int wave = tid >> 6, l = tid & 63, c = l >> 4, f = l & 15;
  int n = blockIdx.x * 4 + wave;
  float beta = beta_p[0];
  float x = 0.f;
  if (n < N) {
    int start = node_start[n], end = node_start[n + 1];
    float den = 0.f, num = 0.f;
    for (int i = start; i < end; ++i) {
      int2 es = sorted[i];
      float qa = q[((size_t)c * N + es.y) * FDIM + f];
      float ea = edge_attr[((size_t)c * E + es.x) * FDIM + f];
      float m2 = qa + ea;
      float ez = __expf(m2 * beta);
      den += ez;
      num = fmaf(m2, ez, num);
    }
    float agg = (den > 0.f) ? num / den : 0.f;
    x = q[((size_t)c * N + n) * FDIM + f] + agg;
  }
  xs[wave][l] = x;
  __syncthreads();
  const unsigned negmask = 0x428Eu;
  float acc = b1s[l];
  #pragma unroll
  for (int ci = 0; ci < 4; ++ci) {
    int wc = c ^ ci;
    float s = ((negmask >> ((c << 2) | ci)) & 1u) ? -1.f : 1.f;
    #pragma unroll
    for (int fi = 0; fi < FDIM; ++fi)
      acc = fmaf(s * xs[wave][ci * FDIM + fi], w1s[wc * 256 + fi * FDIM + f], acc);
  }
  hs[wave][l] = fmaxf(acc, 0.f);
  __syncthreads();
  float acc2 = b2s[l];
  #pragma unroll
  for (int ci = 0; ci < 4; ++ci) {
    int wc = c ^ ci;
    float s = ((negmask >> ((c << 2) | ci)) & 1u) ? -1.f : 1.f;
    #pragma unroll
    for (int fi = 0; fi < FDIM; ++fi)
      acc2 = fmaf(s * hs[wave][ci * FDIM + fi], w2s[wc * 256 + fi * FDIM + f], acc2);
  }
  if (n < N) out[((size_t)c * N + n) * FDIM + f] = acc2;
}

extern "C" void kernel_launch(void* const* d_in, const int* in_sizes, int n_in,
                              void* d_out, int out_size, void* d_ws, size_t ws_size,
                              hipStream_t stream) {
  const float* q         = (const float*)d_in[0];
  const float* edge_attr = (const float*)d_in[1];
  const int*   edge_idx  = (const int*)d_in[2];
  const float* W1        = (const float*)d_in[3];
  const float* b1        = (const float*)d_in[4];
  const float* W2        = (const float*)d_in[5];
  const float* b2        = (const float*)d_in[6];
  const float* beta      = (const float*)d_in[7];

  int N = in_sizes[0] / CF;   // 50000
  int E = in_sizes[2] / 2;    // 800000

  // ws: cursor[N] | wfrag 16KB | qT f16[N*64] | xbuf f16[N*64] | rows f16[N*CAP*64]
  int* cursor = (int*)d_ws;
  size_t off_w = ((size_t)N * sizeof(int) + 255) & ~(size_t)255;
  _Float16* wfrag = (_Float16*)((char*)d_ws + off_w);
  size_t off_q = off_w + 8192 * sizeof(_Float16);
  _Float16* qT = (_Float16*)((char*)d_ws + off_q);
  size_t off_x = off_q + (size_t)N * CF * sizeof(_Float16);
  _Float16* xbuf = (_Float16*)((char*)d_ws + off_x);
  size_t off_r = (off_x + (size_t)N * CF * sizeof(_Float16) + 255) & ~(size_t)255;
  _Float16* rows = (_Float16*)((char*)d_ws + off_r);
  size_t needed = off_r + (size_t)N * CAP * CF * sizeof(_Float16);

  if (ws_size >= needed && (N % 16) == 0) {
    int zb = (N + 255) / 256;                 // cursor-zero blocks
    int qb = (N * 8 + 255) / 256;             // qt blocks
    k_init<<<zb + 32 + qb, 256, 0, stream>>>(cursor, W1, W2, wfrag, q, qT, N, zb);
    k_permute<<<(E + 31) / 32, 256, 0, stream>>>(qT, edge_attr, edge_idx,
                                                 cursor, rows, N, E);
    k_reduce<<<(N + 3) / 4, 256, 0, stream>>>(qT, rows, cursor, beta, xbuf, N);
    k_mlp<<<(N / 16 + 3) / 4, 256, 0, stream>>>(xbuf, wfrag, b1, b2,
                                                (float*)d_out, N);
  } else {
    // fallback: CSR + int2 scatter + fused gather kernel
    int* counts     = (int*)d_ws;
    int* node_start = counts + N;
    size_t off8 = ((size_t)(2 * N + 1) * sizeof(int) + 7) & ~(size_t)7;
    int2* sorted2 = (int2*)((char*)d_ws + off8);
    int eblocks = (E + 255) / 256;
    k_zero<<<(N + 255) / 256, 256, 0, stream>>>(counts, N);
    k_hist<<<eblocks, 256, 0, stream>>>(edge_idx, counts, E);
    k_scan_fb<<<1, 1024, 0, stream>>>(counts, node_start, N, E);
    k_scatter2<<<eblocks, 256, 0, stream>>>(edge_idx, counts, sorted2, E);
    k_node<<<(N + 3) / 4, 256, 0, stream>>>(q, edge_attr, sorted2, node_start,
                                            beta, W1, b1, W2, b2,
                                            (float*)d_out, N, E);
  }
}